// Round 9
// baseline (170.008 us; speedup 1.0000x reference)
//
#include <hip/hip_runtime.h>
#include <hip/hip_bf16.h>
#include <cstdint>
#include <cstddef>

#define N_PTS 4096
#define KDIM  512
#define GRID_BLKS 512   // 2 blocks/CU x 256 CUs — exactly co-resident capacity

typedef __attribute__((ext_vector_type(8))) short bf16x8;   // 8 bf16 = 4 VGPRs
typedef __attribute__((ext_vector_type(4))) float f32x4;
typedef uint32_t u32;

// round-to-nearest-even fp32 -> bf16 (inputs finite)
__device__ inline unsigned short f2bf(float f) {
  union { float f; u32 u; } v; v.f = f;
  u32 r = (v.u + 0x7fffu + ((v.u >> 16) & 1u)) >> 16;
  return (unsigned short)r;
}

// ---------------------------------------------------------------------------
// Kernel 1: repack X (fp32, row-major) into FRAGMENT-MAJOR bf16 Xf and
// compute row squared norms. Xf[(p*16 + c)*512 + l*8 .. +8] holds
// X[p*16 + (l&15)][c*32 + (l>>4)*8 .. +8] — the mfma_16x16x32_bf16 A/B
// fragment for 16-row panel p, 32-k chunk c, lane l. One wave per row.
// Also zeroes gsum and the grid-barrier counter (stream-ordered before fused).
// ---------------------------------------------------------------------------
__global__ __launch_bounds__(256) void prep_kernel(const float* __restrict__ X,
                                                   short* __restrict__ Xf,
                                                   float* __restrict__ sq,
                                                   float* __restrict__ gsum,
                                                   u32* __restrict__ bar) {
  const int t = threadIdx.x;
  if (blockIdx.x == 0 && t == 0) { *gsum = 0.f; *bar = 0u; }
  const int r = blockIdx.x * 4 + (t >> 6);   // wave handles row r
  const int g = t & 63;                      // 8-element k-granule
  const float* src = X + (size_t)r * KDIM + g * 8;
  const float4 u0 = ((const float4*)src)[0];
  const float4 u1 = ((const float4*)src)[1];
  union { unsigned short s[8]; uint4 q; } pk;
  pk.s[0] = f2bf(u0.x); pk.s[1] = f2bf(u0.y);
  pk.s[2] = f2bf(u0.z); pk.s[3] = f2bf(u0.w);
  pk.s[4] = f2bf(u1.x); pk.s[5] = f2bf(u1.y);
  pk.s[6] = f2bf(u1.z); pk.s[7] = f2bf(u1.w);
  const int p = r >> 4, c = g >> 2, l = ((g & 3) << 4) | (r & 15);
  *(uint4*)(Xf + (size_t)(p * 16 + c) * 512 + l * 8) = pk.q;
  float s = u0.x * u0.x + u0.y * u0.y + u0.z * u0.z + u0.w * u0.w +
            u1.x * u1.x + u1.y * u1.y + u1.z * u1.z + u1.w * u1.w;
#pragma unroll
  for (int off = 32; off; off >>= 1) s += __shfl_down(s, off);
  if (g == 0) sq[r] = s;
}

// ---------------------------------------------------------------------------
// Kernel 2 (FUSED, manual grid barrier): 512 blocks, __launch_bounds__(256,2)
// guarantees 2 blocks/CU schedulable -> all 512 co-resident (none exits
// before the barrier), so the atomic arrive-and-spin barrier cannot deadlock.
// Each block: two adjacent 128x128 tiles (bm, bn0|bn0+1) sharing the A panel
// (12 frag loads : 32 MFMAs per 32-k chunk). Phase A: GEMM both tiles,
// d=sqrt(max(sqi+sqj-2dot,0)) in-register, block sum -> device atomicAdd.
// Barrier. Phase B: bw from gsum; out = w^4+w^2+w+sqrt(w)+sqrt(sqrt(w)),
// w=exp(-d/bw) (bandwidth multipliers are exactly 2^{f-2}); direct fp32 out.
// No Dw intermediate (R4-R7's 66 MB round-trip eliminated).
// ---------------------------------------------------------------------------
__global__ __launch_bounds__(256, 2) void fused_kernel(
    const short* __restrict__ Xf, const float* __restrict__ sq,
    float* __restrict__ gsum, u32* __restrict__ bar, float* __restrict__ out) {
  __shared__ float red[4];
  const int tid = threadIdx.x;
  const int lane = tid & 63;
  const int wid = tid >> 6;
  const int wave_m = wid >> 1, wave_n = wid & 1;
  const int lhi = lane >> 4, llo = lane & 15;
  const int blk = blockIdx.x;        // 0..511
  const int bm = blk >> 4;           // 0..31
  const int bn0 = (blk & 15) << 1;   // 0,2,..,30 ; tiles bn0 and bn0+1

  // panel stride = 16*512 = 8192 shorts; chunk stride = 512 shorts
  const short* baseA = Xf + (size_t)(bm * 8 + wave_m * 4) * 8192 + lane * 8;
  const short* baseB = Xf + (size_t)(bn0 * 8 + wave_n * 4) * 8192 + lane * 8;

  f32x4 acc0[4][4], acc1[4][4];
#pragma unroll
  for (int i = 0; i < 4; ++i)
#pragma unroll
    for (int j = 0; j < 4; ++j) {
      acc0[i][j] = (f32x4){0.f, 0.f, 0.f, 0.f};
      acc1[i][j] = (f32x4){0.f, 0.f, 0.f, 0.f};
    }

#pragma unroll
  for (int c = 0; c < 16; ++c) {
    bf16x8 av[4], b0v[4], b1v[4];
#pragma unroll
    for (int i = 0; i < 4; ++i) {
      av[i]  = *(const bf16x8*)(baseA + c * 512 + (size_t)i * 8192);
      b0v[i] = *(const bf16x8*)(baseB + c * 512 + (size_t)i * 8192);
      b1v[i] = *(const bf16x8*)(baseB + c * 512 + (size_t)(8 + i) * 8192);
    }
#pragma unroll
    for (int i = 0; i < 4; ++i)
#pragma unroll
      for (int j = 0; j < 4; ++j) {
        acc0[i][j] =
            __builtin_amdgcn_mfma_f32_16x16x32_bf16(av[i], b0v[j], acc0[i][j], 0, 0, 0);
        acc1[i][j] =
            __builtin_amdgcn_mfma_f32_16x16x32_bf16(av[i], b1v[j], acc1[i][j], 0, 0, 0);
      }
  }

  // ---- Phase A epilogue: d in-register (C/D: col=lane&15, row=(lane>>4)*4+reg)
  float lsum = 0.f;
  const int gi_base = bm * 128 + wave_m * 64 + lhi * 4;
  const int c0 = bn0 * 128 + wave_n * 64 + llo;
  const int c1 = c0 + 128;
  float sqj0[4], sqj1[4];
#pragma unroll
  for (int j = 0; j < 4; ++j) {
    sqj0[j] = sq[c0 + j * 16];
    sqj1[j] = sq[c1 + j * 16];
  }

#pragma unroll
  for (int i = 0; i < 4; ++i) {
#pragma unroll
    for (int rr = 0; rr < 4; ++rr) {
      const int gi = gi_base + i * 16 + rr;
      const float sqi = sq[gi];
#pragma unroll
      for (int j = 0; j < 4; ++j) {
        float d2a = sqi + sqj0[j] - 2.f * acc0[i][j][rr];
        float da = __builtin_amdgcn_sqrtf(fmaxf(d2a, 0.f));
        if (gi == c0 + j * 16) da = 0.f;   // exact-zero diagonal
        lsum += da;
        acc0[i][j][rr] = da;

        float d2b = sqi + sqj1[j] - 2.f * acc1[i][j][rr];
        float db = __builtin_amdgcn_sqrtf(fmaxf(d2b, 0.f));
        if (gi == c1 + j * 16) db = 0.f;
        lsum += db;
        acc1[i][j][rr] = db;
      }
    }
  }
#pragma unroll
  for (int off = 32; off; off >>= 1) lsum += __shfl_down(lsum, off);
  if (lane == 0) red[wid] = lsum;
  __syncthreads();

  // ---- manual grid barrier (all 512 blocks co-resident by construction) ----
  if (tid == 0) {
    atomicAdd(gsum, red[0] + red[1] + red[2] + red[3]);  // device-scope
    __threadfence();                                     // release sum
    __hip_atomic_fetch_add(bar, 1u, __ATOMIC_ACQ_REL, __HIP_MEMORY_SCOPE_AGENT);
    while (__hip_atomic_load(bar, __ATOMIC_ACQUIRE, __HIP_MEMORY_SCOPE_AGENT) <
           (u32)GRID_BLKS) { __builtin_amdgcn_s_sleep(8); }
  }
  __syncthreads();

  // ---- Phase B: bandwidth, exp-sum, direct fp32 store ----
  const float total = __hip_atomic_load(gsum, __ATOMIC_RELAXED,
                                        __HIP_MEMORY_SCOPE_AGENT);
  const float cinv = -((float)N_PTS * (float)(N_PTS - 1)) / total;  // = -1/bw

#pragma unroll
  for (int i = 0; i < 4; ++i) {
#pragma unroll
    for (int rr = 0; rr < 4; ++rr) {
      const int gi = gi_base + i * 16 + rr;
      float* orow0 = out + (size_t)gi * N_PTS + c0;
      float* orow1 = out + (size_t)gi * N_PTS + c1;
#pragma unroll
      for (int j = 0; j < 4; ++j) {
        {
          const float w = __expf(acc0[i][j][rr] * cinv);
          const float s1 = __builtin_amdgcn_sqrtf(w);
          const float s2 = __builtin_amdgcn_sqrtf(s1);
          const float w2 = w * w;
          orow0[j * 16] = w2 * w2 + w2 + w + s1 + s2;  // exps 4,2,1,1/2,1/4
        }
        {
          const float w = __expf(acc1[i][j][rr] * cinv);
          const float s1 = __builtin_amdgcn_sqrtf(w);
          const float s2 = __builtin_amdgcn_sqrtf(s1);
          const float w2 = w * w;
          orow1[j * 16] = w2 * w2 + w2 + w + s1 + s2;
        }
      }
    }
  }
}

extern "C" void kernel_launch(void* const* d_in, const int* in_sizes, int n_in,
                              void* d_out, int out_size, void* d_ws, size_t ws_size,
                              hipStream_t stream) {
  const float* X = (const float*)d_in[0];
  float* out = (float*)d_out;

  // ws: gsum@0 | bar@512 | sq@1024 (16KB) | Xf@17408 (4MB, fragment-major)
  char* ws = (char*)d_ws;
  float* gsum = (float*)ws;
  u32* bar = (u32*)(ws + 512);
  float* sq = (float*)(ws + 1024);
  short* Xf = (short*)(ws + 1024 + N_PTS * sizeof(float));

  prep_kernel<<<N_PTS / 4, 256, 0, stream>>>(X, Xf, sq, gsum, bar);
  fused_kernel<<<GRID_BLKS, 256, 0, stream>>>(Xf, sq, gsum, bar, out);
}